// Round 5
// baseline (116.982 us; speedup 1.0000x reference)
//
#include <hip/hip_runtime.h>
#include <math.h>

// Problem constants
#define B 2
#define N 8192            // points per batch
#define PTS_STRIDE (N*3)
#define VOXEL 0.1f

#define BLK  256
#define PBLK 1024
#define YSPLIT 8
#define YRANGE (N/YSPLIT)   // 1024 y per block

// ws layout (float element offsets). Known from R4: ws_size >= 17 MB; we use ~4.5 MB.
//  [0..15]  gmin[arr][b][3]
//  [16]     acc   [17] ticket
//  OFF_PACK: per g=arr*2+b: Braw[8192]x16B, Bvox, Araw, Avox (short8 each), xxr[8192]f32, xxv[8192]f32
//  OFF_PART: partials float[var(2)][slot(4)][ys(8)][x(8192)]
#define WS_GMIN 0
#define WS_ACC 16
#define WS_TICKET 17
#define OFF_PACK 32
#define PERG 147456
#define OFF_BR(g)  (OFF_PACK + (g)*PERG)
#define OFF_BV(g)  (OFF_BR(g) + 32768)
#define OFF_AR(g)  (OFF_BR(g) + 65536)
#define OFF_AV(g)  (OFF_BR(g) + 98304)
#define OFF_XXR(g) (OFF_BR(g) + 131072)
#define OFF_XXV(g) (OFF_BR(g) + 139264)
#define OFF_PART   (OFF_PACK + 4*PERG)        // 589856
#define PART_IDX(var, slot, ys, x) (OFF_PART + ((((var)*4 + (slot))*YSPLIT + (ys))*N) + (x))

typedef __attribute__((ext_vector_type(8))) short short8;   // 8 bf16 = 4 VGPRs (MFMA A/B frag)
typedef __attribute__((ext_vector_type(4))) float f4;       // MFMA C/D frag

union S8 { short8 v; short s[8]; unsigned short u[8]; };

__device__ __forceinline__ unsigned short f2bf(float f) {   // RNE f32->bf16
    unsigned u = __float_as_uint(f);
    return (unsigned short)((u + 0x7FFFu + ((u >> 16) & 1u)) >> 16);
}
__device__ __forceinline__ float bf2f(unsigned short h) {
    return __uint_as_float(((unsigned)h) << 16);
}
__device__ __forceinline__ float voxq(float v, float g) {
    return (float)(int)((v - g) / VOXEL);   // trunc like .astype(int32)
}

__global__ void __launch_bounds__(PBLK)
prep_kernel(const float* __restrict__ preds,
            const float* __restrict__ gts,
            float* __restrict__ ws) {
    const int g   = blockIdx.x;        // g = arr*2 + b
    const int arr = g >> 1;
    const int b   = g & 1;
    const float* base = (arr ? gts : preds) + b * PTS_STRIDE;

    // --- per-(arr,b) coordinate min (NaN -> inf) ---
    float m0 = INFINITY, m1 = INFINITY, m2 = INFINITY;
    for (int i = threadIdx.x; i < N; i += PBLK) {
        float v0 = base[i*3+0], v1 = base[i*3+1], v2 = base[i*3+2];
        v0 = (v0 != v0) ? INFINITY : v0;
        v1 = (v1 != v1) ? INFINITY : v1;
        v2 = (v2 != v2) ? INFINITY : v2;
        m0 = fminf(m0, v0); m1 = fminf(m1, v1); m2 = fminf(m2, v2);
    }
    for (int off = 32; off; off >>= 1) {
        m0 = fminf(m0, __shfl_down(m0, off));
        m1 = fminf(m1, __shfl_down(m1, off));
        m2 = fminf(m2, __shfl_down(m2, off));
    }
    __shared__ float sm[16][3];
    __shared__ float gsh[3];
    const int wave = threadIdx.x >> 6, lane = threadIdx.x & 63;
    if (lane == 0) { sm[wave][0] = m0; sm[wave][1] = m1; sm[wave][2] = m2; }
    __syncthreads();
    if (threadIdx.x == 0) {
        float a0 = sm[0][0], a1 = sm[0][1], a2 = sm[0][2];
        for (int w = 1; w < 16; ++w) {
            a0 = fminf(a0, sm[w][0]);
            a1 = fminf(a1, sm[w][1]);
            a2 = fminf(a2, sm[w][2]);
        }
        ws[WS_GMIN + g*3+0] = a0; ws[WS_GMIN + g*3+1] = a1; ws[WS_GMIN + g*3+2] = a2;
        gsh[0] = a0; gsh[1] = a1; gsh[2] = a2;
        if (g == 0) { ws[WS_ACC] = 0.0f; ((unsigned*)ws)[WS_TICKET] = 0u; }
    }
    __syncthreads();

    // --- pack MFMA fragments + fp32 |p|^2 ---
    const float g0 = gsh[0], g1 = gsh[1], g2 = gsh[2];
    short8* BR = (short8*)(ws + OFF_BR(g));
    short8* BV = (short8*)(ws + OFF_BV(g));
    short8* AR = (short8*)(ws + OFF_AR(g));
    short8* AV = (short8*)(ws + OFF_AV(g));
    float*  XR = ws + OFF_XXR(g);
    float*  XV = ws + OFF_XXV(g);
    const unsigned short ONE = 0x3F80;   // bf16 1.0

    for (int i = threadIdx.x; i < N; i += PBLK) {
        const float p0 = base[i*3+0], p1 = base[i*3+1], p2 = base[i*3+2];
        const float v0 = voxq(p0, g0), v1 = voxq(p1, g1), v2 = voxq(p2, g2);
        const float rr = fmaf(p0,p0, fmaf(p1,p1, p2*p2));
        const float vv = fmaf(v0,v0, fmaf(v1,v1, v2*v2));
        XR[i] = rr; XV[i] = vv;

        S8 a; S8 bb;
        // A-frag raw: [x0,x1,x2,1,1,0,0,0]
        a.u[0]=f2bf(p0); a.u[1]=f2bf(p1); a.u[2]=f2bf(p2);
        a.u[3]=ONE; a.u[4]=ONE; a.u[5]=0; a.u[6]=0; a.u[7]=0;
        AR[i] = a.v;
        // B-frag raw: [-2y0,-2y1,-2y2, yy_hi, yy_lo, 0,0,0]
        unsigned short hh = f2bf(rr);
        bb.u[0]=f2bf(-2.0f*p0); bb.u[1]=f2bf(-2.0f*p1); bb.u[2]=f2bf(-2.0f*p2);
        bb.u[3]=hh; bb.u[4]=f2bf(rr - bf2f(hh)); bb.u[5]=0; bb.u[6]=0; bb.u[7]=0;
        BR[i] = bb.v;
        // A-frag vox
        a.u[0]=f2bf(v0); a.u[1]=f2bf(v1); a.u[2]=f2bf(v2);
        a.u[3]=ONE; a.u[4]=ONE; a.u[5]=0; a.u[6]=0; a.u[7]=0;
        AV[i] = a.v;
        // B-frag vox (exact: ints, residual int < 64)
        hh = f2bf(vv);
        bb.u[0]=f2bf(-2.0f*v0); bb.u[1]=f2bf(-2.0f*v1); bb.u[2]=f2bf(-2.0f*v2);
        bb.u[3]=hh; bb.u[4]=f2bf(vv - bf2f(hh)); bb.u[5]=0; bb.u[6]=0; bb.u[7]=0;
        BV[i] = bb.v;
    }
}

// MFMA chamfer: grid (32 xgroups, 8 ysplits, 4 slots), 256 threads.
// Each wave owns 4 x-tiles of 16 rows; loops 64 y-tiles of its 1024-y range.
// A-frags: quads>=1 zeroed, so B can be read quad-replicated (k>=8 products vanish).
__global__ void __launch_bounds__(BLK, 4)
chamfer_kernel(float* __restrict__ ws) {
    const int tid  = threadIdx.x;
    const int wave = tid >> 6, lane = tid & 63;
    const int quad = lane >> 4, c16 = lane & 15;
    const int dir  = blockIdx.z & 1;
    const int b    = blockIdx.z >> 1;
    const int slot = blockIdx.z;
    const int gX = dir*2 + b;        // X = preds (dir0) / gts (dir1)
    const int gY = (1-dir)*2 + b;

    const short8* AR = (const short8*)(ws + OFF_AR(gX));
    const short8* AV = (const short8*)(ws + OFF_AV(gX));
    const short8* BR = (const short8*)(ws + OFF_BR(gY));
    const short8* BV = (const short8*)(ws + OFF_BV(gY));

    const int xwave = blockIdx.x * BLK + wave * 64;   // this wave's 64 x-points
    short8 aR[4], aV[4];
#pragma unroll
    for (int t = 0; t < 4; ++t) {
        const int xi = xwave + t*16 + c16;
        short8 r = AR[xi], v = AV[xi];
        if (quad != 0) { r = (short8)0; v = (short8)0; }   // A zero at k>=8
        aR[t] = r; aV[t] = v;
    }

    f4 mR[4], mV[4];
#pragma unroll
    for (int t = 0; t < 4; ++t) {
        mR[t] = (f4){INFINITY, INFINITY, INFINITY, INFINITY};
        mV[t] = (f4){INFINITY, INFINITY, INFINITY, INFINITY};
    }
    const f4 zero = (f4){0.f, 0.f, 0.f, 0.f};

    const int ybase = blockIdx.y * YRANGE;
    for (int yt = 0; yt < YRANGE/16; yt += 2) {
        const int y0 = ybase + yt*16 + c16;
        const short8 bR0 = BR[y0], bR1 = BR[y0 + 16];
        const short8 bV0 = BV[y0], bV1 = BV[y0 + 16];
#pragma unroll
        for (int t = 0; t < 4; ++t) {
            f4 d0 = __builtin_amdgcn_mfma_f32_16x16x32_bf16(aR[t], bR0, zero, 0, 0, 0);
            f4 d1 = __builtin_amdgcn_mfma_f32_16x16x32_bf16(aR[t], bR1, zero, 0, 0, 0);
#pragma unroll
            for (int r = 0; r < 4; ++r)
                mR[t][r] = fminf(mR[t][r], fminf(d0[r], d1[r]));   // -> v_min3
            f4 e0 = __builtin_amdgcn_mfma_f32_16x16x32_bf16(aV[t], bV0, zero, 0, 0, 0);
            f4 e1 = __builtin_amdgcn_mfma_f32_16x16x32_bf16(aV[t], bV1, zero, 0, 0, 0);
#pragma unroll
            for (int r = 0; r < 4; ++r)
                mV[t][r] = fminf(mV[t][r], fminf(e0[r], e1[r]));
        }
    }

    // Epilogue: min over 16 cols (lanes within quad), add |x|^2 (fp32), store partials.
    // C/D layout: col = lane&15 (y), row = quad*4 + r (x within tile).
    const float* XXR = ws + OFF_XXR(gX);
    const float* XXV = ws + OFF_XXV(gX);
#pragma unroll
    for (int t = 0; t < 4; ++t) {
#pragma unroll
        for (int r = 0; r < 4; ++r) {
            float vr = mR[t][r], vv = mV[t][r];
            for (int s = 1; s < 16; s <<= 1) {
                vr = fminf(vr, __shfl_xor(vr, s));
                vv = fminf(vv, __shfl_xor(vv, s));
            }
            if (c16 == 0) {
                const int x = xwave + t*16 + quad*4 + r;
                ws[PART_IDX(0, slot, blockIdx.y, x)] = vr + XXR[x];
                ws[PART_IDX(1, slot, blockIdx.y, x)] = vv + XXV[x];
            }
        }
    }
}

// 128 blocks x 256: one thread per (slot,x). Min over ysplits, sum, reduce, ticket-out.
__global__ void __launch_bounds__(BLK)
finalize_kernel(float* __restrict__ ws, float* __restrict__ out) {
    const int g = blockIdx.x * BLK + threadIdx.x;   // 0..32767
    const int slot = g >> 13;
    const int x    = g & (N-1);
    float m_r = INFINITY, m_v = INFINITY;
#pragma unroll
    for (int ys = 0; ys < YSPLIT; ++ys) {
        m_r = fminf(m_r, ws[PART_IDX(0, slot, ys, x)]);
        m_v = fminf(m_v, ws[PART_IDX(1, slot, ys, x)]);
    }
    float s = m_r + m_v;
    for (int off = 32; off; off >>= 1)
        s += __shfl_down(s, off);
    __shared__ float sm[4];
    const int wave = threadIdx.x >> 6, lane = threadIdx.x & 63;
    if (lane == 0) sm[wave] = s;
    __syncthreads();
    if (threadIdx.x == 0) {
        const float bs = sm[0] + sm[1] + sm[2] + sm[3];
        atomicAdd(ws + WS_ACC, bs);
        __threadfence();
        const unsigned t = atomicAdd(&((unsigned*)ws)[WS_TICKET], 1u);
        if (t == gridDim.x - 1) {
            __threadfence();
            const float total = atomicAdd(ws + WS_ACC, 0.0f);  // atomic read
            out[0] = total * (1.0f / 16384.0f);
        }
    }
}

extern "C" void kernel_launch(void* const* d_in, const int* in_sizes, int n_in,
                              void* d_out, int out_size, void* d_ws, size_t ws_size,
                              hipStream_t stream) {
    const float* preds = (const float*)d_in[0];
    const float* gts   = (const float*)d_in[1];
    float* ws  = (float*)d_ws;
    float* out = (float*)d_out;

    prep_kernel<<<dim3(4), dim3(PBLK), 0, stream>>>(preds, gts, ws);
    chamfer_kernel<<<dim3(N/BLK, YSPLIT, 4), dim3(BLK), 0, stream>>>(ws);
    finalize_kernel<<<dim3(32768/BLK), dim3(BLK), 0, stream>>>(ws, out);
}

// Round 6
// 109.826 us; speedup vs baseline: 1.0652x; 1.0652x over previous
//
#include <hip/hip_runtime.h>
#include <math.h>

// Problem constants
#define B 2
#define N 8192            // points per batch
#define PTS_STRIDE (N*3)
#define VOXEL 0.1f

#define BLK  256          // chamfer block = 4 waves
#define PBLK 1024
#define YSPLIT 16
#define YRANGE (N/YSPLIT) // 512 y per block
#define XPB 128           // x per block (4 waves x 32)
#define XTILES (N/XPB)    // 64

// ws layout (float offsets); known ws_size >= 17 MB, we use ~4.2 MB.
//  [0..15] gmin[arr][b][3]   [16] acc   [17] ticket
//  OFF_PART: partials float[var(2)][slot(4)][ys(16)][x(8192)]
#define WS_GMIN 0
#define WS_ACC 16
#define WS_TICKET 17
#define OFF_PART 32
#define PART_IDX(var, slot, ys, x) (OFF_PART + ((((var)*4 + (slot))*YSPLIT + (ys))*N) + (x))

typedef __attribute__((ext_vector_type(8))) short short8;    // 8 bf16 (MFMA A/B frag)
typedef __attribute__((ext_vector_type(16))) float f16v;     // 32x32 MFMA C/D frag

union S8 { short8 v; unsigned short u[8]; };

__device__ __forceinline__ unsigned short f2bf(float f) {    // RNE f32->bf16
    unsigned u = __float_as_uint(f);
    return (unsigned short)((u + 0x7FFFu + ((u >> 16) & 1u)) >> 16);
}
__device__ __forceinline__ float bf2f(unsigned short h) {
    return __uint_as_float(((unsigned)h) << 16);
}
__device__ __forceinline__ float voxq(float v, float g) {
    return (float)(int)((v - g) / VOXEL);   // trunc like .astype(int32)
}

__global__ void __launch_bounds__(PBLK)
gmin_kernel(const float* __restrict__ preds,
            const float* __restrict__ gts,
            float* __restrict__ ws) {
    const int g   = blockIdx.x;        // g = arr*2 + b
    const int arr = g >> 1;
    const int b   = g & 1;
    const float* base = (arr ? gts : preds) + b * PTS_STRIDE;

    float m0 = INFINITY, m1 = INFINITY, m2 = INFINITY;
    for (int i = threadIdx.x; i < N; i += PBLK) {
        float v0 = base[i*3+0], v1 = base[i*3+1], v2 = base[i*3+2];
        v0 = (v0 != v0) ? INFINITY : v0;   // NaN -> inf (matches masked_fill)
        v1 = (v1 != v1) ? INFINITY : v1;
        v2 = (v2 != v2) ? INFINITY : v2;
        m0 = fminf(m0, v0); m1 = fminf(m1, v1); m2 = fminf(m2, v2);
    }
    for (int off = 32; off; off >>= 1) {
        m0 = fminf(m0, __shfl_down(m0, off));
        m1 = fminf(m1, __shfl_down(m1, off));
        m2 = fminf(m2, __shfl_down(m2, off));
    }
    __shared__ float sm[16][3];
    const int wave = threadIdx.x >> 6, lane = threadIdx.x & 63;
    if (lane == 0) { sm[wave][0] = m0; sm[wave][1] = m1; sm[wave][2] = m2; }
    __syncthreads();
    if (threadIdx.x == 0) {
        float a0 = sm[0][0], a1 = sm[0][1], a2 = sm[0][2];
        for (int w = 1; w < 16; ++w) {
            a0 = fminf(a0, sm[w][0]);
            a1 = fminf(a1, sm[w][1]);
            a2 = fminf(a2, sm[w][2]);
        }
        ws[WS_GMIN + g*3+0] = a0; ws[WS_GMIN + g*3+1] = a1; ws[WS_GMIN + g*3+2] = a2;
        if (g == 0) { ws[WS_ACC] = 0.0f; ((unsigned*)ws)[WS_TICKET] = 0u; }
    }
}

// MFMA chamfer, transposed: A rows = y (staged in LDS as bf16 frags),
// B cols = x (per-lane registers). D[m][n] = |y_m|^2 - 2 x_n . y_m ;
// min over rows m = in-lane min over the 16 C-regs + one shfl_xor(32).
// A-frag(y) = [y0,y1,y2,yy_hi,yy_lo,0,0,0]; B-frag(x) = [-2x0,-2x1,-2x2,1,1,0,0,0].
// B upper half-wave (k=8..15) zeroed so A can be read uniformly from LDS.
__global__ void __launch_bounds__(BLK)
chamfer_kernel(const float* __restrict__ preds,
               const float* __restrict__ gts,
               float* __restrict__ ws) {
    const int tid  = threadIdx.x;
    const int wave = tid >> 6, lane = tid & 63;
    const int half = lane >> 5, c32 = lane & 31;
    const int dir  = blockIdx.z & 1;
    const int b    = blockIdx.z >> 1;
    const int slot = blockIdx.z;
    const float* X = (dir ? gts : preds) + b * PTS_STRIDE;
    const float* Y = (dir ? preds : gts) + b * PTS_STRIDE;
    const int arrX = dir, arrY = 1 - dir;

    const float gx0 = ws[WS_GMIN + (arrX*2+b)*3+0];
    const float gx1 = ws[WS_GMIN + (arrX*2+b)*3+1];
    const float gx2 = ws[WS_GMIN + (arrX*2+b)*3+2];
    const float gy0 = ws[WS_GMIN + (arrY*2+b)*3+0];
    const float gy1 = ws[WS_GMIN + (arrY*2+b)*3+1];
    const float gy2 = ws[WS_GMIN + (arrY*2+b)*3+2];

    __shared__ short8 ldsR[YRANGE];   // 8 KB
    __shared__ short8 ldsV[YRANGE];   // 8 KB
    const unsigned short ONE = 0x3F80;

    // stage this block's 512 y-points as A-frags (raw + vox), built on the fly
    const int ybase = blockIdx.y * YRANGE;
    for (int i = tid; i < YRANGE; i += BLK) {
        const int yi = ybase + i;
        const float y0 = Y[yi*3+0], y1 = Y[yi*3+1], y2 = Y[yi*3+2];
        const float yy = fmaf(y0,y0, fmaf(y1,y1, y2*y2));
        S8 fr;
        unsigned short hh = f2bf(yy);
        fr.u[0]=f2bf(y0); fr.u[1]=f2bf(y1); fr.u[2]=f2bf(y2);
        fr.u[3]=hh; fr.u[4]=f2bf(yy - bf2f(hh)); fr.u[5]=0; fr.u[6]=0; fr.u[7]=0;
        ldsR[i] = fr.v;
        const float v0 = voxq(y0, gy0), v1 = voxq(y1, gy1), v2 = voxq(y2, gy2);
        const float vv = fmaf(v0,v0, fmaf(v1,v1, v2*v2));
        hh = f2bf(vv);
        fr.u[0]=f2bf(v0); fr.u[1]=f2bf(v1); fr.u[2]=f2bf(v2);
        fr.u[3]=hh; fr.u[4]=f2bf(vv - bf2f(hh)); fr.u[5]=0; fr.u[6]=0; fr.u[7]=0;
        ldsV[i] = fr.v;
    }

    // B-frags: this lane's x-point (col n = c32); zero for upper half (k>=8)
    const int xi = blockIdx.x * XPB + wave * 32 + c32;
    const float p0 = X[xi*3+0], p1 = X[xi*3+1], p2 = X[xi*3+2];
    const float xxr = fmaf(p0,p0, fmaf(p1,p1, p2*p2));
    const float w0 = voxq(p0, gx0), w1 = voxq(p1, gx1), w2 = voxq(p2, gx2);
    const float xxv = fmaf(w0,w0, fmaf(w1,w1, w2*w2));
    S8 sb;
    sb.u[0]=f2bf(-2.0f*p0); sb.u[1]=f2bf(-2.0f*p1); sb.u[2]=f2bf(-2.0f*p2);
    sb.u[3]=ONE; sb.u[4]=ONE; sb.u[5]=0; sb.u[6]=0; sb.u[7]=0;
    short8 bR = half ? (short8)0 : sb.v;
    sb.u[0]=f2bf(-2.0f*w0); sb.u[1]=f2bf(-2.0f*w1); sb.u[2]=f2bf(-2.0f*w2);
    sb.u[3]=ONE; sb.u[4]=ONE; sb.u[5]=0; sb.u[6]=0; sb.u[7]=0;
    short8 bV = half ? (short8)0 : sb.v;

    __syncthreads();

    f16v mR = (f16v)(INFINITY);
    f16v mV = (f16v)(INFINITY);
    const f16v Z = (f16v)(0.0f);

    for (int yt = 0; yt < YRANGE/32; yt += 2) {       // 8 bodies, 2 y-tiles each
        const short8 aR0 = ldsR[yt*32 + c32];
        const short8 aR1 = ldsR[yt*32 + 32 + c32];
        const short8 aV0 = ldsV[yt*32 + c32];
        const short8 aV1 = ldsV[yt*32 + 32 + c32];
        const f16v d0 = __builtin_amdgcn_mfma_f32_32x32x16_bf16(aR0, bR, Z, 0, 0, 0);
        const f16v d1 = __builtin_amdgcn_mfma_f32_32x32x16_bf16(aR1, bR, Z, 0, 0, 0);
#pragma unroll
        for (int r = 0; r < 16; ++r)
            mR[r] = fminf(mR[r], fminf(d0[r], d1[r]));    // -> v_min3
        const f16v e0 = __builtin_amdgcn_mfma_f32_32x32x16_bf16(aV0, bV, Z, 0, 0, 0);
        const f16v e1 = __builtin_amdgcn_mfma_f32_32x32x16_bf16(aV1, bV, Z, 0, 0, 0);
#pragma unroll
        for (int r = 0; r < 16; ++r)
            mV[r] = fminf(mV[r], fminf(e0[r], e1[r]));
    }

    // Epilogue: min over rows (16 regs in-lane, then the other half via xor-32),
    // add |x|^2, coalesced store of this lane's x partial.
    float rmin = mR[0], vmin = mV[0];
#pragma unroll
    for (int r = 1; r < 16; ++r) {
        rmin = fminf(rmin, mR[r]);
        vmin = fminf(vmin, mV[r]);
    }
    rmin = fminf(rmin, __shfl_xor(rmin, 32));
    vmin = fminf(vmin, __shfl_xor(vmin, 32));
    if (half == 0) {
        ws[PART_IDX(0, slot, blockIdx.y, xi)] = rmin + xxr;
        ws[PART_IDX(1, slot, blockIdx.y, xi)] = vmin + xxv;
    }
}

// 128 blocks x 256: one thread per (slot,x). Min over ysplits, sum, reduce, ticket-out.
__global__ void __launch_bounds__(BLK)
finalize_kernel(float* __restrict__ ws, float* __restrict__ out) {
    const int g = blockIdx.x * BLK + threadIdx.x;   // 0..32767
    const int slot = g >> 13;
    const int x    = g & (N-1);
    float m_r = INFINITY, m_v = INFINITY;
#pragma unroll
    for (int ys = 0; ys < YSPLIT; ++ys) {
        m_r = fminf(m_r, ws[PART_IDX(0, slot, ys, x)]);
        m_v = fminf(m_v, ws[PART_IDX(1, slot, ys, x)]);
    }
    float s = m_r + m_v;
    for (int off = 32; off; off >>= 1)
        s += __shfl_down(s, off);
    __shared__ float sm[4];
    const int wave = threadIdx.x >> 6, lane = threadIdx.x & 63;
    if (lane == 0) sm[wave] = s;
    __syncthreads();
    if (threadIdx.x == 0) {
        const float bs = sm[0] + sm[1] + sm[2] + sm[3];
        atomicAdd(ws + WS_ACC, bs);
        __threadfence();
        const unsigned t = atomicAdd(&((unsigned*)ws)[WS_TICKET], 1u);
        if (t == gridDim.x - 1) {
            __threadfence();
            const float total = atomicAdd(ws + WS_ACC, 0.0f);  // atomic read
            out[0] = total * (1.0f / 16384.0f);
        }
    }
}

extern "C" void kernel_launch(void* const* d_in, const int* in_sizes, int n_in,
                              void* d_out, int out_size, void* d_ws, size_t ws_size,
                              hipStream_t stream) {
    const float* preds = (const float*)d_in[0];
    const float* gts   = (const float*)d_in[1];
    float* ws  = (float*)d_ws;
    float* out = (float*)d_out;

    gmin_kernel<<<dim3(4), dim3(PBLK), 0, stream>>>(preds, gts, ws);
    chamfer_kernel<<<dim3(XTILES, YSPLIT, 4), dim3(BLK), 0, stream>>>(preds, gts, ws);
    finalize_kernel<<<dim3(32768/BLK), dim3(BLK), 0, stream>>>(ws, out);
}

// Round 7
// 108.035 us; speedup vs baseline: 1.0828x; 1.0166x over previous
//
#include <hip/hip_runtime.h>
#include <math.h>

// Problem constants
#define B 2
#define N 8192            // points per batch
#define PTS_STRIDE (N*3)
#define VOXEL 0.1f

#define BLK  256          // 4 waves
#define YSPLIT 16
#define YRANGE (N/YSPLIT) // 512 y per block
#define XPB 64            // x per block: 4 waves x 16 x-points
#define XTILES (N/XPB)    // 128

// ws layout (float offsets); ws_size >= 17 MB known, we use ~6.6 MB.
//  [0..15] unused  [16] acc  [17] ticket
//  OFF_PACK per g=arr*2+b (PERG floats):
//    AFLO[N]  short8: [y0,y1,y2,yyh,yyl, w0,w1,w2]      (A half0)
//    AFHI[N]  short8: [vvh,vvl,0,...]                   (A half1)
//    BR[N]    short8: [-2x0,-2x1,-2x2,1,1,0,0,0]        (B raw col, half0)
//    BVLO[N]  short8: [0,0,0,0,0,-2u0,-2u1,-2u2]        (B vox col, half0)
//    XXR[N], XXV[N] f32
//  OFF_PART: partials float[var(2)][slot(4)][ys(16)][x(8192)]  (4 MB)
#define WS_ACC 16
#define WS_TICKET 17
#define OFF_PACK 32
#define PERG 147456
#define OFF_AFLO(g) (OFF_PACK + (g)*PERG)
#define OFF_AFHI(g) (OFF_AFLO(g) + 32768)
#define OFF_BR(g)   (OFF_AFLO(g) + 65536)
#define OFF_BVLO(g) (OFF_AFLO(g) + 98304)
#define OFF_XXR(g)  (OFF_AFLO(g) + 131072)
#define OFF_XXV(g)  (OFF_AFLO(g) + 139264)
#define OFF_PART    (OFF_PACK + 4*PERG)
#define PART_IDX(var, slot, ys, x) (OFF_PART + ((((var)*4 + (slot))*YSPLIT + (ys))*N) + (x))

typedef __attribute__((ext_vector_type(8))) short short8;    // 8 bf16 (MFMA A/B frag)
typedef __attribute__((ext_vector_type(16))) float f16v;     // 32x32 MFMA C/D frag

union S8 { short8 v; unsigned short u[8]; };

__device__ __forceinline__ unsigned short f2bf(float f) {    // RNE f32->bf16
    unsigned u = __float_as_uint(f);
    return (unsigned short)((u + 0x7FFFu + ((u >> 16) & 1u)) >> 16);
}
__device__ __forceinline__ float bf2f(unsigned short h) {
    return __uint_as_float(((unsigned)h) << 16);
}
__device__ __forceinline__ float voxq(float v, float g) {
    return (float)(int)((v - g) / VOXEL);   // trunc like .astype(int32)
}

// 32 blocks: g = blk>>3 (arr*2+b), chunk = blk&7 (1024 points).
// Each block: full-batch gmin reduce (redundant, cheap) then packs its chunk.
__global__ void __launch_bounds__(BLK)
pack_kernel(const float* __restrict__ preds,
            const float* __restrict__ gts,
            float* __restrict__ ws) {
    const int g     = blockIdx.x >> 3;
    const int chunk = blockIdx.x & 7;
    const int arr = g >> 1;
    const int b   = g & 1;
    const float* base = (arr ? gts : preds) + b * PTS_STRIDE;

    // --- gmin over the whole batch (NaN -> inf) ---
    float m0 = INFINITY, m1 = INFINITY, m2 = INFINITY;
    for (int i = threadIdx.x; i < N; i += BLK) {
        float v0 = base[i*3+0], v1 = base[i*3+1], v2 = base[i*3+2];
        v0 = (v0 != v0) ? INFINITY : v0;
        v1 = (v1 != v1) ? INFINITY : v1;
        v2 = (v2 != v2) ? INFINITY : v2;
        m0 = fminf(m0, v0); m1 = fminf(m1, v1); m2 = fminf(m2, v2);
    }
    for (int off = 32; off; off >>= 1) {
        m0 = fminf(m0, __shfl_down(m0, off));
        m1 = fminf(m1, __shfl_down(m1, off));
        m2 = fminf(m2, __shfl_down(m2, off));
    }
    __shared__ float sm[4][3];
    __shared__ float gsh[3];
    const int wave = threadIdx.x >> 6, lane = threadIdx.x & 63;
    if (lane == 0) { sm[wave][0] = m0; sm[wave][1] = m1; sm[wave][2] = m2; }
    __syncthreads();
    if (threadIdx.x == 0) {
        gsh[0] = fminf(fminf(sm[0][0], sm[1][0]), fminf(sm[2][0], sm[3][0]));
        gsh[1] = fminf(fminf(sm[0][1], sm[1][1]), fminf(sm[2][1], sm[3][1]));
        gsh[2] = fminf(fminf(sm[0][2], sm[1][2]), fminf(sm[2][2], sm[3][2]));
        if (blockIdx.x == 0) { ws[WS_ACC] = 0.0f; ((unsigned*)ws)[WS_TICKET] = 0u; }
    }
    __syncthreads();
    const float g0 = gsh[0], g1 = gsh[1], g2 = gsh[2];

    // --- pack this chunk's 1024 points ---
    short8* AFLO = (short8*)(ws + OFF_AFLO(g));
    short8* AFHI = (short8*)(ws + OFF_AFHI(g));
    short8* BR   = (short8*)(ws + OFF_BR(g));
    short8* BVLO = (short8*)(ws + OFF_BVLO(g));
    float*  XXR  = ws + OFF_XXR(g);
    float*  XXV  = ws + OFF_XXV(g);
    const unsigned short ONE = 0x3F80;

    for (int i = chunk*1024 + threadIdx.x; i < (chunk+1)*1024; i += BLK) {
        const float p0 = base[i*3+0], p1 = base[i*3+1], p2 = base[i*3+2];
        const float w0 = voxq(p0, g0), w1 = voxq(p1, g1), w2 = voxq(p2, g2);
        const float rr = fmaf(p0,p0, fmaf(p1,p1, p2*p2));
        const float vv = fmaf(w0,w0, fmaf(w1,w1, w2*w2));
        XXR[i] = rr; XXV[i] = vv;

        const unsigned short yyh = f2bf(rr);
        const unsigned short yyl = f2bf(rr - bf2f(yyh));
        const unsigned short vvh = f2bf(vv);
        const unsigned short vvl = f2bf(vv - bf2f(vvh));

        S8 f;
        // A half0: [y0,y1,y2,yyh,yyl, w0,w1,w2]
        f.u[0]=f2bf(p0); f.u[1]=f2bf(p1); f.u[2]=f2bf(p2);
        f.u[3]=yyh; f.u[4]=yyl;
        f.u[5]=f2bf(w0); f.u[6]=f2bf(w1); f.u[7]=f2bf(w2);
        AFLO[i] = f.v;
        // A half1: [vvh,vvl,0...]
        f.u[0]=vvh; f.u[1]=vvl; f.u[2]=0; f.u[3]=0; f.u[4]=0; f.u[5]=0; f.u[6]=0; f.u[7]=0;
        AFHI[i] = f.v;
        // B raw col half0: [-2x,1,1,0,0,0]
        f.u[0]=f2bf(-2.0f*p0); f.u[1]=f2bf(-2.0f*p1); f.u[2]=f2bf(-2.0f*p2);
        f.u[3]=ONE; f.u[4]=ONE; f.u[5]=0; f.u[6]=0; f.u[7]=0;
        BR[i] = f.v;
        // B vox col half0: [0,0,0,0,0,-2u]
        f.u[0]=0; f.u[1]=0; f.u[2]=0; f.u[3]=0; f.u[4]=0;
        f.u[5]=f2bf(-2.0f*w0); f.u[6]=f2bf(-2.0f*w1); f.u[7]=f2bf(-2.0f*w2);
        BVLO[i] = f.v;
    }
}

// Transposed MFMA chamfer, raw+vox fused in one mfma_32x32x16:
// A rows = 32 y (LDS), B cols: n<16 raw x_n, n>=16 vox x_{n-16}.
// Each MFMA folds immediately into ONE running scalar per lane.
__global__ void __launch_bounds__(BLK)
chamfer_kernel(float* __restrict__ ws) {
    const int tid  = threadIdx.x;
    const int wave = tid >> 6, lane = tid & 63;
    const int half = lane >> 5, c32 = lane & 31;
    const int dir  = blockIdx.z & 1;
    const int b    = blockIdx.z >> 1;
    const int slot = blockIdx.z;
    const int gX = dir*2 + b;
    const int gY = (1-dir)*2 + b;

    const short8* AFLO = (const short8*)(ws + OFF_AFLO(gY));
    const short8* AFHI = (const short8*)(ws + OFF_AFHI(gY));
    const short8* BR   = (const short8*)(ws + OFF_BR(gX));
    const short8* BVLO = (const short8*)(ws + OFF_BVLO(gX));

    __shared__ short8 ldsLo[YRANGE];   // 8 KB
    __shared__ short8 ldsHi[YRANGE];   // 8 KB

    const int ybase = blockIdx.y * YRANGE;
    for (int i = tid; i < YRANGE; i += BLK) {
        ldsLo[i] = AFLO[ybase + i];
        ldsHi[i] = AFHI[ybase + i];
    }

    // B-frag: per-lane single load from selected address; half1 is const/zero
    const int n = c32;
    const int xi = blockIdx.x * XPB + wave * 16 + (n & 15);
    const short8* bp = (n < 16) ? (BR + xi) : (BVLO + xi);
    short8 bfrag = *bp;
    if (half) {
        S8 h;
        h.u[0] = (n < 16) ? (unsigned short)0 : (unsigned short)0x3F80;
        h.u[1] = h.u[0];
        h.u[2]=0; h.u[3]=0; h.u[4]=0; h.u[5]=0; h.u[6]=0; h.u[7]=0;
        bfrag = h.v;
    }

    __syncthreads();

    const short8* aBase = half ? ldsHi : ldsLo;   // per-lane LDS base
    const f16v Z = (f16v)(0.0f);                  // dedicated zero C block
    float mn = INFINITY;

#pragma unroll 4
    for (int yt = 0; yt < YRANGE/32; ++yt) {      // 16 MFMAs
        const short8 af = aBase[yt*32 + c32];
        const f16v d = __builtin_amdgcn_mfma_f32_32x32x16_bf16(af, bfrag, Z, 0, 0, 0);
        // fold 16 outputs -> running scalar (v_min3 tree)
        float t0 = fminf(fminf(d[0], d[1]),  fminf(d[2], d[3]));
        float t1 = fminf(fminf(d[4], d[5]),  fminf(d[6], d[7]));
        float t2 = fminf(fminf(d[8], d[9]),  fminf(d[10], d[11]));
        float t3 = fminf(fminf(d[12], d[13]), fminf(d[14], d[15]));
        mn = fminf(mn, fminf(fminf(t0, t1), fminf(t2, t3)));
    }

    // other 16 rows live in the xor-32 partner lane (same column)
    mn = fminf(mn, __shfl_xor(mn, 32));

    if (half == 0) {
        const float* XX = (n < 16) ? (ws + OFF_XXR(gX)) : (ws + OFF_XXV(gX));
        const int var = (n < 16) ? 0 : 1;
        ws[PART_IDX(var, slot, blockIdx.y, xi)] = mn + XX[xi];
    }
}

// 128 blocks x 256: one thread per (slot,x). Min over ysplits, sum, reduce, ticket-out.
__global__ void __launch_bounds__(BLK)
finalize_kernel(float* __restrict__ ws, float* __restrict__ out) {
    const int g = blockIdx.x * BLK + threadIdx.x;   // 0..32767
    const int slot = g >> 13;
    const int x    = g & (N-1);
    float m_r = INFINITY, m_v = INFINITY;
#pragma unroll
    for (int ys = 0; ys < YSPLIT; ++ys) {
        m_r = fminf(m_r, ws[PART_IDX(0, slot, ys, x)]);
        m_v = fminf(m_v, ws[PART_IDX(1, slot, ys, x)]);
    }
    float s = m_r + m_v;
    for (int off = 32; off; off >>= 1)
        s += __shfl_down(s, off);
    __shared__ float sm[4];
    const int wave = threadIdx.x >> 6, lane = threadIdx.x & 63;
    if (lane == 0) sm[wave] = s;
    __syncthreads();
    if (threadIdx.x == 0) {
        const float bs = sm[0] + sm[1] + sm[2] + sm[3];
        atomicAdd(ws + WS_ACC, bs);
        __threadfence();
        const unsigned t = atomicAdd(&((unsigned*)ws)[WS_TICKET], 1u);
        if (t == gridDim.x - 1) {
            __threadfence();
            const float total = atomicAdd(ws + WS_ACC, 0.0f);  // atomic read
            out[0] = total * (1.0f / 16384.0f);
        }
    }
}

extern "C" void kernel_launch(void* const* d_in, const int* in_sizes, int n_in,
                              void* d_out, int out_size, void* d_ws, size_t ws_size,
                              hipStream_t stream) {
    const float* preds = (const float*)d_in[0];
    const float* gts   = (const float*)d_in[1];
    float* ws  = (float*)d_ws;
    float* out = (float*)d_out;

    pack_kernel<<<dim3(32), dim3(BLK), 0, stream>>>(preds, gts, ws);
    chamfer_kernel<<<dim3(XTILES, YSPLIT, 4), dim3(BLK), 0, stream>>>(ws);
    finalize_kernel<<<dim3(32768/BLK), dim3(BLK), 0, stream>>>(ws, out);
}

// Round 8
// 97.288 us; speedup vs baseline: 1.2024x; 1.1105x over previous
//
#include <hip/hip_runtime.h>
#include <math.h>

// Problem constants
#define B 2
#define N 8192            // points per batch
#define PTS_STRIDE (N*3)
#define VOXEL 0.1f

#define BLK  256          // 4 waves
#define PBLK 1024
#define XPB 64            // x per block (4 fused B-frags per wave)
#define XTILES (N/XPB)    // 128
#define NBLOCKS (XTILES*4)  // 512 chamfer blocks
#define CH 128            // y per staged chunk per wave

// ws layout (float offsets); ws_size >= 17 MB known, we use ~2.4 MB.
//  [0..11] gmin[g][3]   [16] acc   [17] ticket
//  OFF_PACK per g=arr*2+b (PERG=147456 floats):
//    AF[N][2] short8 interleaved: [y0,y1,y2,yyh,yyl,w0,w1,w2] then [vvh,vvl,0..]
//    BR[N]   short8: [-2x0,-2x1,-2x2,1,1,0,0,0]
//    BV[N]   short8: [0,0,0,0,0,-2u0,-2u1,-2u2]
//    XXR[N], XXV[N] f32
#define WS_GMIN 0
#define WS_ACC 16
#define WS_TICKET 17
#define OFF_PACK 32
#define PERG 147456
#define OFF_AF(g)  (OFF_PACK + (g)*PERG)
#define OFF_BR(g)  (OFF_AF(g) + 65536)
#define OFF_BV(g)  (OFF_BR(g) + 32768)
#define OFF_XXR(g) (OFF_BV(g) + 32768)
#define OFF_XXV(g) (OFF_XXR(g) + 8192)

typedef __attribute__((ext_vector_type(8))) short short8;    // 8 bf16 (MFMA A/B frag)
typedef __attribute__((ext_vector_type(16))) float f16v;     // 32x32 MFMA C/D frag

union S8 { short8 v; unsigned short u[8]; };

__device__ __forceinline__ unsigned short f2bf(float f) {    // RNE f32->bf16
    unsigned u = __float_as_uint(f);
    return (unsigned short)((u + 0x7FFFu + ((u >> 16) & 1u)) >> 16);
}
__device__ __forceinline__ float bf2f(unsigned short h) {
    return __uint_as_float(((unsigned)h) << 16);
}
__device__ __forceinline__ float voxq(float v, float g) {
    return (float)(int)((v - g) / VOXEL);   // trunc like .astype(int32)
}

__global__ void __launch_bounds__(PBLK)
gmin_kernel(const float* __restrict__ preds,
            const float* __restrict__ gts,
            float* __restrict__ ws) {
    const int g   = blockIdx.x;        // g = arr*2 + b
    const int arr = g >> 1;
    const int b   = g & 1;
    const float* base = (arr ? gts : preds) + b * PTS_STRIDE;

    float m0 = INFINITY, m1 = INFINITY, m2 = INFINITY;
    for (int i = threadIdx.x; i < N; i += PBLK) {
        float v0 = base[i*3+0], v1 = base[i*3+1], v2 = base[i*3+2];
        v0 = (v0 != v0) ? INFINITY : v0;   // NaN -> inf (matches masked_fill)
        v1 = (v1 != v1) ? INFINITY : v1;
        v2 = (v2 != v2) ? INFINITY : v2;
        m0 = fminf(m0, v0); m1 = fminf(m1, v1); m2 = fminf(m2, v2);
    }
    for (int off = 32; off; off >>= 1) {
        m0 = fminf(m0, __shfl_down(m0, off));
        m1 = fminf(m1, __shfl_down(m1, off));
        m2 = fminf(m2, __shfl_down(m2, off));
    }
    __shared__ float sm[16][3];
    const int wave = threadIdx.x >> 6, lane = threadIdx.x & 63;
    if (lane == 0) { sm[wave][0] = m0; sm[wave][1] = m1; sm[wave][2] = m2; }
    __syncthreads();
    if (threadIdx.x == 0) {
        float a0 = sm[0][0], a1 = sm[0][1], a2 = sm[0][2];
        for (int w = 1; w < 16; ++w) {
            a0 = fminf(a0, sm[w][0]);
            a1 = fminf(a1, sm[w][1]);
            a2 = fminf(a2, sm[w][2]);
        }
        ws[WS_GMIN + g*3+0] = a0; ws[WS_GMIN + g*3+1] = a1; ws[WS_GMIN + g*3+2] = a2;
        if (g == 0) { ws[WS_ACC] = 0.0f; ((unsigned*)ws)[WS_TICKET] = 0u; }
    }
}

// One thread per point (128 blocks x 256 = 32768): build all fragments.
__global__ void __launch_bounds__(BLK)
pack_kernel(const float* __restrict__ preds,
            const float* __restrict__ gts,
            float* __restrict__ ws) {
    const int i   = blockIdx.x * BLK + threadIdx.x;   // 0..32767
    const int g   = i >> 13;
    const int idx = i & (N-1);
    const int arr = g >> 1;
    const int b   = g & 1;
    const float* base = (arr ? gts : preds) + b * PTS_STRIDE;

    const float g0 = ws[WS_GMIN + g*3+0];
    const float g1 = ws[WS_GMIN + g*3+1];
    const float g2 = ws[WS_GMIN + g*3+2];

    const float p0 = base[idx*3+0], p1 = base[idx*3+1], p2 = base[idx*3+2];
    const float w0 = voxq(p0, g0), w1 = voxq(p1, g1), w2 = voxq(p2, g2);
    const float rr = fmaf(p0,p0, fmaf(p1,p1, p2*p2));
    const float vv = fmaf(w0,w0, fmaf(w1,w1, w2*w2));

    const unsigned short yyh = f2bf(rr);
    const unsigned short yyl = f2bf(rr - bf2f(yyh));
    const unsigned short vvh = f2bf(vv);
    const unsigned short vvl = f2bf(vv - bf2f(vvh));
    const unsigned short ONE = 0x3F80;

    short8* AF = (short8*)(ws + OFF_AF(g));
    short8* BR = (short8*)(ws + OFF_BR(g));
    short8* BV = (short8*)(ws + OFF_BV(g));

    S8 f;
    // A lo (k=0..7): [y0,y1,y2,yyh,yyl, w0,w1,w2]
    f.u[0]=f2bf(p0); f.u[1]=f2bf(p1); f.u[2]=f2bf(p2);
    f.u[3]=yyh; f.u[4]=yyl; f.u[5]=f2bf(w0); f.u[6]=f2bf(w1); f.u[7]=f2bf(w2);
    AF[idx*2] = f.v;
    // A hi (k=8..15): [vvh,vvl,0...]
    f.u[0]=vvh; f.u[1]=vvl; f.u[2]=0; f.u[3]=0; f.u[4]=0; f.u[5]=0; f.u[6]=0; f.u[7]=0;
    AF[idx*2+1] = f.v;
    // B raw col (k=0..7)
    f.u[0]=f2bf(-2.0f*p0); f.u[1]=f2bf(-2.0f*p1); f.u[2]=f2bf(-2.0f*p2);
    f.u[3]=ONE; f.u[4]=ONE; f.u[5]=0; f.u[6]=0; f.u[7]=0;
    BR[idx] = f.v;
    // B vox col (k=0..7)
    f.u[0]=0; f.u[1]=0; f.u[2]=0; f.u[3]=0; f.u[4]=0;
    f.u[5]=f2bf(-2.0f*w0); f.u[6]=f2bf(-2.0f*w1); f.u[7]=f2bf(-2.0f*w2);
    BV[idx] = f.v;
    ws[OFF_XXR(g) + idx] = rr;
    ws[OFF_XXV(g) + idx] = vv;
}

// One-pass chamfer: 512 blocks = 4 slots x 128 x-tiles (64 x each).
// Wave w covers y in [w*2048,(w+1)*2048), staged wave-synchronously (no barriers).
// B cols: n<16 raw x_n, n>=16 vox x_{n-16}; 4 B-frags per wave (4-way ILP).
// Epilogue: cross-wave LDS min, add |x|^2, block sum, atomicAdd + ticket-out.
__global__ void __launch_bounds__(BLK, 2)
chamfer_kernel(float* __restrict__ ws, float* __restrict__ out) {
    const int tid  = threadIdx.x;
    const int wave = tid >> 6, lane = tid & 63;
    const int half = lane >> 5, c32 = lane & 31;
    const int slot = blockIdx.y;           // 0..3 : dir*1 + b*2
    const int dir  = slot & 1;
    const int b    = slot >> 1;
    const int gX = dir*2 + b;
    const int gY = (1-dir)*2 + b;

    const short8* AF = (const short8*)(ws + OFF_AF(gY));
    const short8* BR = (const short8*)(ws + OFF_BR(gX));
    const short8* BV = (const short8*)(ws + OFF_BV(gX));

    __shared__ short8 lds[4][CH*2];        // 16 KB: per-wave staging region
    __shared__ float smin[4][4][32];       // wave x bf x col
    __shared__ float ssum[2];

    // 4 fused B-frags for this wave's 64 x
    const int xbase = blockIdx.x * XPB;
    short8 bf[4];
    S8 hc;
    hc.u[0] = (c32 < 16) ? (unsigned short)0 : (unsigned short)0x3F80;
    hc.u[1] = hc.u[0];
    hc.u[2]=0; hc.u[3]=0; hc.u[4]=0; hc.u[5]=0; hc.u[6]=0; hc.u[7]=0;
#pragma unroll
    for (int f = 0; f < 4; ++f) {
        const int xi = xbase + f*16 + (c32 & 15);
        if (half == 0) {
            bf[f] = (c32 < 16) ? BR[xi] : BV[xi];
        } else {
            bf[f] = hc.v;     // k=8,9: 0 for raw cols, 1.0 for vox cols
        }
    }

    float mn0 = INFINITY, mn1 = INFINITY, mn2 = INFINITY, mn3 = INFINITY;
    const f16v Z = (f16v)(0.0f);
    const int ybase = wave * 2048;

    for (int c = 0; c < 2048/CH; ++c) {           // 16 chunks
        // wave-synchronous stage: CH points x 2 frags = 256 x 16B
        const int fbase = (ybase + c*CH) * 2;
#pragma unroll
        for (int j = 0; j < 4; ++j)
            lds[wave][lane + j*64] = AF[fbase + lane + j*64];
        // no barrier: this wave wrote and reads its own region

#pragma unroll
        for (int t = 0; t < CH/32; ++t) {         // 4 A-tiles of 32 y
            const short8 a = lds[wave][(t*32 + c32)*2 + half];
            const f16v d0 = __builtin_amdgcn_mfma_f32_32x32x16_bf16(a, bf[0], Z, 0, 0, 0);
            const f16v d1 = __builtin_amdgcn_mfma_f32_32x32x16_bf16(a, bf[1], Z, 0, 0, 0);
            const f16v d2 = __builtin_amdgcn_mfma_f32_32x32x16_bf16(a, bf[2], Z, 0, 0, 0);
            const f16v d3 = __builtin_amdgcn_mfma_f32_32x32x16_bf16(a, bf[3], Z, 0, 0, 0);
#pragma unroll
            for (int r = 0; r < 16; r += 4) {
                mn0 = fminf(mn0, fminf(fminf(d0[r], d0[r+1]), fminf(d0[r+2], d0[r+3])));
                mn1 = fminf(mn1, fminf(fminf(d1[r], d1[r+1]), fminf(d1[r+2], d1[r+3])));
                mn2 = fminf(mn2, fminf(fminf(d2[r], d2[r+1]), fminf(d2[r+2], d2[r+3])));
                mn3 = fminf(mn3, fminf(fminf(d3[r], d3[r+1]), fminf(d3[r+2], d3[r+3])));
            }
        }
    }

    // fold the other 16 rows (xor-32 partner holds same column, other half-rows)
    mn0 = fminf(mn0, __shfl_xor(mn0, 32));
    mn1 = fminf(mn1, __shfl_xor(mn1, 32));
    mn2 = fminf(mn2, __shfl_xor(mn2, 32));
    mn3 = fminf(mn3, __shfl_xor(mn3, 32));
    if (half == 0) {
        smin[wave][0][c32] = mn0;
        smin[wave][1][c32] = mn1;
        smin[wave][2][c32] = mn2;
        smin[wave][3][c32] = mn3;
    }
    __syncthreads();

    // threads 0..127: one per (bf, col) -> min over 4 waves, add |x|^2, sum
    if (tid < 128) {
        const int f   = tid >> 5;
        const int col = tid & 31;
        float v = fminf(fminf(smin[0][f][col], smin[1][f][col]),
                        fminf(smin[2][f][col], smin[3][f][col]));
        const int xi = xbase + f*16 + (col & 15);
        v += (col < 16) ? ws[OFF_XXR(gX) + xi] : ws[OFF_XXV(gX) + xi];
        for (int off = 32; off; off >>= 1)
            v += __shfl_down(v, off);
        if ((tid & 63) == 0) ssum[tid >> 6] = v;
    }
    __syncthreads();
    if (tid == 0) {
        const float bs = ssum[0] + ssum[1];
        atomicAdd(ws + WS_ACC, bs);
        __threadfence();
        const unsigned t = atomicAdd(&((unsigned*)ws)[WS_TICKET], 1u);
        if (t == NBLOCKS - 1) {
            __threadfence();
            const float total = atomicAdd(ws + WS_ACC, 0.0f);  // atomic read
            out[0] = total * (1.0f / 16384.0f);
        }
    }
}

extern "C" void kernel_launch(void* const* d_in, const int* in_sizes, int n_in,
                              void* d_out, int out_size, void* d_ws, size_t ws_size,
                              hipStream_t stream) {
    const float* preds = (const float*)d_in[0];
    const float* gts   = (const float*)d_in[1];
    float* ws  = (float*)d_ws;
    float* out = (float*)d_out;

    gmin_kernel<<<dim3(4), dim3(PBLK), 0, stream>>>(preds, gts, ws);
    pack_kernel<<<dim3(128), dim3(BLK), 0, stream>>>(preds, gts, ws);
    chamfer_kernel<<<dim3(XTILES, 4), dim3(BLK), 0, stream>>>(ws, out);
}

// Round 9
// 96.039 us; speedup vs baseline: 1.2181x; 1.0130x over previous
//
#include <hip/hip_runtime.h>
#include <math.h>

// Problem constants
#define B 2
#define N 8192            // points per batch
#define PTS_STRIDE (N*3)
#define VOXEL 0.1f

#define BLK  512          // chamfer: 8 waves, each owns a 1024-y range
#define PBLK 1024
#define XPB 64            // x per block (4 fused B-frags per wave)
#define XTILES (N/XPB)    // 128
#define NBLOCKS (XTILES*4)  // 512 chamfer blocks

// ws layout (float offsets); ws_size >= 17 MB known, we use ~2.4 MB.
//  [0..11] gmin[g][3]   [16] acc   [17] ticket
//  OFF_PACK per g=arr*2+b (PERG=147456 floats):
//    AFLO[N] short8: [y0,y1,y2,yyh,yyl,w0,w1,w2]   (A rows, k=0..7)
//    AFHI[N] short8: [vvh,vvl,0,...]               (A rows, k=8..15)
//    BR[N]   short8: [-2x0,-2x1,-2x2,1,1,0,0,0]    (B raw col, k=0..7)
//    BV[N]   short8: [0,0,0,0,0,-2u0,-2u1,-2u2]    (B vox col, k=0..7)
//    XXR[N], XXV[N] f32
#define WS_GMIN 0
#define WS_ACC 16
#define WS_TICKET 17
#define OFF_PACK 32
#define PERG 147456
#define OFF_AFLO(g) (OFF_PACK + (g)*PERG)
#define OFF_AFHI(g) (OFF_AFLO(g) + 32768)
#define OFF_BR(g)   (OFF_AFLO(g) + 65536)
#define OFF_BV(g)   (OFF_AFLO(g) + 98304)
#define OFF_XXR(g)  (OFF_AFLO(g) + 131072)
#define OFF_XXV(g)  (OFF_AFLO(g) + 139264)

typedef __attribute__((ext_vector_type(8))) short short8;    // 8 bf16 (MFMA A/B frag)
typedef __attribute__((ext_vector_type(16))) float f16v;     // 32x32 MFMA C/D frag

union S8 { short8 v; unsigned short u[8]; };

__device__ __forceinline__ unsigned short f2bf(float f) {    // RNE f32->bf16
    unsigned u = __float_as_uint(f);
    return (unsigned short)((u + 0x7FFFu + ((u >> 16) & 1u)) >> 16);
}
__device__ __forceinline__ float bf2f(unsigned short h) {
    return __uint_as_float(((unsigned)h) << 16);
}
__device__ __forceinline__ float voxq(float v, float g) {
    return (float)(int)((v - g) / VOXEL);   // trunc like .astype(int32)
}

__global__ void __launch_bounds__(PBLK)
gmin_kernel(const float* __restrict__ preds,
            const float* __restrict__ gts,
            float* __restrict__ ws) {
    const int g   = blockIdx.x;        // g = arr*2 + b
    const int arr = g >> 1;
    const int b   = g & 1;
    const float* base = (arr ? gts : preds) + b * PTS_STRIDE;

    float m0 = INFINITY, m1 = INFINITY, m2 = INFINITY;
    for (int i = threadIdx.x; i < N; i += PBLK) {
        float v0 = base[i*3+0], v1 = base[i*3+1], v2 = base[i*3+2];
        v0 = (v0 != v0) ? INFINITY : v0;   // NaN -> inf (matches masked_fill)
        v1 = (v1 != v1) ? INFINITY : v1;
        v2 = (v2 != v2) ? INFINITY : v2;
        m0 = fminf(m0, v0); m1 = fminf(m1, v1); m2 = fminf(m2, v2);
    }
    for (int off = 32; off; off >>= 1) {
        m0 = fminf(m0, __shfl_down(m0, off));
        m1 = fminf(m1, __shfl_down(m1, off));
        m2 = fminf(m2, __shfl_down(m2, off));
    }
    __shared__ float sm[16][3];
    const int wave = threadIdx.x >> 6, lane = threadIdx.x & 63;
    if (lane == 0) { sm[wave][0] = m0; sm[wave][1] = m1; sm[wave][2] = m2; }
    __syncthreads();
    if (threadIdx.x == 0) {
        float a0 = sm[0][0], a1 = sm[0][1], a2 = sm[0][2];
        for (int w = 1; w < 16; ++w) {
            a0 = fminf(a0, sm[w][0]);
            a1 = fminf(a1, sm[w][1]);
            a2 = fminf(a2, sm[w][2]);
        }
        ws[WS_GMIN + g*3+0] = a0; ws[WS_GMIN + g*3+1] = a1; ws[WS_GMIN + g*3+2] = a2;
        if (g == 0) { ws[WS_ACC] = 0.0f; ((unsigned*)ws)[WS_TICKET] = 0u; }
    }
}

// One thread per point (128 blocks x 256 = 32768): build all fragments.
__global__ void __launch_bounds__(256)
pack_kernel(const float* __restrict__ preds,
            const float* __restrict__ gts,
            float* __restrict__ ws) {
    const int i   = blockIdx.x * 256 + threadIdx.x;   // 0..32767
    const int g   = i >> 13;
    const int idx = i & (N-1);
    const int arr = g >> 1;
    const int b   = g & 1;
    const float* base = (arr ? gts : preds) + b * PTS_STRIDE;

    const float g0 = ws[WS_GMIN + g*3+0];
    const float g1 = ws[WS_GMIN + g*3+1];
    const float g2 = ws[WS_GMIN + g*3+2];

    const float p0 = base[idx*3+0], p1 = base[idx*3+1], p2 = base[idx*3+2];
    const float w0 = voxq(p0, g0), w1 = voxq(p1, g1), w2 = voxq(p2, g2);
    const float rr = fmaf(p0,p0, fmaf(p1,p1, p2*p2));
    const float vv = fmaf(w0,w0, fmaf(w1,w1, w2*w2));

    const unsigned short yyh = f2bf(rr);
    const unsigned short yyl = f2bf(rr - bf2f(yyh));
    const unsigned short vvh = f2bf(vv);
    const unsigned short vvl = f2bf(vv - bf2f(vvh));
    const unsigned short ONE = 0x3F80;

    short8* AFLO = (short8*)(ws + OFF_AFLO(g));
    short8* AFHI = (short8*)(ws + OFF_AFHI(g));
    short8* BR   = (short8*)(ws + OFF_BR(g));
    short8* BV   = (short8*)(ws + OFF_BV(g));

    S8 f;
    // A lo (k=0..7): [y0,y1,y2,yyh,yyl, w0,w1,w2]
    f.u[0]=f2bf(p0); f.u[1]=f2bf(p1); f.u[2]=f2bf(p2);
    f.u[3]=yyh; f.u[4]=yyl; f.u[5]=f2bf(w0); f.u[6]=f2bf(w1); f.u[7]=f2bf(w2);
    AFLO[idx] = f.v;
    // A hi (k=8..15): [vvh,vvl,0...]
    f.u[0]=vvh; f.u[1]=vvl; f.u[2]=0; f.u[3]=0; f.u[4]=0; f.u[5]=0; f.u[6]=0; f.u[7]=0;
    AFHI[idx] = f.v;
    // B raw col (k=0..7)
    f.u[0]=f2bf(-2.0f*p0); f.u[1]=f2bf(-2.0f*p1); f.u[2]=f2bf(-2.0f*p2);
    f.u[3]=ONE; f.u[4]=ONE; f.u[5]=0; f.u[6]=0; f.u[7]=0;
    BR[idx] = f.v;
    // B vox col (k=0..7)
    f.u[0]=0; f.u[1]=0; f.u[2]=0; f.u[3]=0; f.u[4]=0;
    f.u[5]=f2bf(-2.0f*w0); f.u[6]=f2bf(-2.0f*w1); f.u[7]=f2bf(-2.0f*w2);
    BV[idx] = f.v;
    ws[OFF_XXR(g) + idx] = rr;
    ws[OFF_XXV(g) + idx] = vv;
}

// One-pass chamfer, no hot-loop LDS: 512 blocks = 4 slots x 128 x-tiles.
// 8 waves/block; wave w owns y in [w*1024,(w+1)*1024). A-frags loaded straight
// from global (coalesced 16B/lane; lane c32 reads point t*32+c32, half selects
// lo/hi array). B cols: n<16 raw x_n, n>=16 vox x_{n-16}; 4 B-frags per wave.
// Epilogue: cross-wave LDS min, add |x|^2, block sum, atomicAdd + ticket-out.
__global__ void __launch_bounds__(BLK, 4)
chamfer_kernel(float* __restrict__ ws, float* __restrict__ out) {
    const int tid  = threadIdx.x;
    const int wave = tid >> 6, lane = tid & 63;
    const int half = lane >> 5, c32 = lane & 31;
    const int slot = blockIdx.y;           // 0..3
    const int dir  = slot & 1;
    const int b    = slot >> 1;
    const int gX = dir*2 + b;
    const int gY = (1-dir)*2 + b;

    const short8* ALO = (const short8*)(ws + OFF_AFLO(gY));
    const short8* AHI = (const short8*)(ws + OFF_AFHI(gY));
    const short8* Abase = half ? AHI : ALO;
    const short8* BR = (const short8*)(ws + OFF_BR(gX));
    const short8* BV = (const short8*)(ws + OFF_BV(gX));

    __shared__ float smin[8][4][32];       // wave x bf x col (4 KB)
    __shared__ float ssum[2];

    // 4 fused B-frags for this block's 64 x
    const int xbase = blockIdx.x * XPB;
    short8 bf[4];
    S8 hc;
    hc.u[0] = (c32 < 16) ? (unsigned short)0 : (unsigned short)0x3F80;
    hc.u[1] = hc.u[0];
    hc.u[2]=0; hc.u[3]=0; hc.u[4]=0; hc.u[5]=0; hc.u[6]=0; hc.u[7]=0;
#pragma unroll
    for (int f = 0; f < 4; ++f) {
        const int xi = xbase + f*16 + (c32 & 15);
        bf[f] = (half == 0) ? ((c32 < 16) ? BR[xi] : BV[xi]) : hc.v;
    }

    float mn0 = INFINITY, mn1 = INFINITY, mn2 = INFINITY, mn3 = INFINITY;
    const f16v Z = (f16v)(0.0f);
    const int abase0 = wave * 1024 + c32;  // this lane's first A index

#pragma unroll 2
    for (int t = 0; t < 32; ++t) {         // 32 y-tiles of 32
        const short8 a = Abase[abase0 + t*32];
        const f16v d0 = __builtin_amdgcn_mfma_f32_32x32x16_bf16(a, bf[0], Z, 0, 0, 0);
        const f16v d1 = __builtin_amdgcn_mfma_f32_32x32x16_bf16(a, bf[1], Z, 0, 0, 0);
        const f16v d2 = __builtin_amdgcn_mfma_f32_32x32x16_bf16(a, bf[2], Z, 0, 0, 0);
        const f16v d3 = __builtin_amdgcn_mfma_f32_32x32x16_bf16(a, bf[3], Z, 0, 0, 0);
#pragma unroll
        for (int r = 0; r < 16; r += 4) {
            mn0 = fminf(mn0, fminf(fminf(d0[r], d0[r+1]), fminf(d0[r+2], d0[r+3])));
            mn1 = fminf(mn1, fminf(fminf(d1[r], d1[r+1]), fminf(d1[r+2], d1[r+3])));
            mn2 = fminf(mn2, fminf(fminf(d2[r], d2[r+1]), fminf(d2[r+2], d2[r+3])));
            mn3 = fminf(mn3, fminf(fminf(d3[r], d3[r+1]), fminf(d3[r+2], d3[r+3])));
        }
    }

    // fold the other 16 rows (xor-32 partner holds same column, other half-rows)
    mn0 = fminf(mn0, __shfl_xor(mn0, 32));
    mn1 = fminf(mn1, __shfl_xor(mn1, 32));
    mn2 = fminf(mn2, __shfl_xor(mn2, 32));
    mn3 = fminf(mn3, __shfl_xor(mn3, 32));
    if (half == 0) {
        smin[wave][0][c32] = mn0;
        smin[wave][1][c32] = mn1;
        smin[wave][2][c32] = mn2;
        smin[wave][3][c32] = mn3;
    }
    __syncthreads();

    // threads 0..127: one per (bf, col) -> min over 8 waves, add |x|^2, sum
    if (tid < 128) {
        const int f   = tid >> 5;
        const int col = tid & 31;
        float v = smin[0][f][col];
#pragma unroll
        for (int w = 1; w < 8; ++w) v = fminf(v, smin[w][f][col]);
        const int xi = xbase + f*16 + (col & 15);
        v += (col < 16) ? ws[OFF_XXR(gX) + xi] : ws[OFF_XXV(gX) + xi];
        for (int off = 32; off; off >>= 1)
            v += __shfl_down(v, off);
        if ((tid & 63) == 0) ssum[tid >> 6] = v;
    }
    __syncthreads();
    if (tid == 0) {
        const float bs = ssum[0] + ssum[1];
        atomicAdd(ws + WS_ACC, bs);
        __threadfence();
        const unsigned t = atomicAdd(&((unsigned*)ws)[WS_TICKET], 1u);
        if (t == NBLOCKS - 1) {
            __threadfence();
            const float total = atomicAdd(ws + WS_ACC, 0.0f);  // atomic read
            out[0] = total * (1.0f / 16384.0f);
        }
    }
}

extern "C" void kernel_launch(void* const* d_in, const int* in_sizes, int n_in,
                              void* d_out, int out_size, void* d_ws, size_t ws_size,
                              hipStream_t stream) {
    const float* preds = (const float*)d_in[0];
    const float* gts   = (const float*)d_in[1];
    float* ws  = (float*)d_ws;
    float* out = (float*)d_out;

    gmin_kernel<<<dim3(4), dim3(PBLK), 0, stream>>>(preds, gts, ws);
    pack_kernel<<<dim3(128), dim3(256), 0, stream>>>(preds, gts, ws);
    chamfer_kernel<<<dim3(XTILES, 4), dim3(BLK), 0, stream>>>(ws, out);
}

// Round 10
// 91.015 us; speedup vs baseline: 1.2853x; 1.0552x over previous
//
#include <hip/hip_runtime.h>
#include <math.h>

// Problem constants
#define B 2
#define N 8192            // points per batch
#define PTS_STRIDE (N*3)
#define VOXEL 0.1f

#define CBLK 128          // chamfer: 2 waves per block, no LDS, no barriers
#define PBLK 1024

// ws layout (float offsets); ws_size >= 17 MB known, we use ~2.7 MB.
//  [16] acc   [17] ticket   [20..31] gmin[g][3]
//  WS_MINS: uint mins[slot(4)][var(2)][x(8192)]  (monotone-encoded float, init 0xFF800000)
//  OFF_PACK per g=arr*2+b (PERG=147456 floats):
//    AFLO[N] short8: [y0,y1,y2,yyh,yyl,w0,w1,w2]   (A rows, k=0..7)
//    AFHI[N] short8: [vvh,vvl,0,...]               (A rows, k=8..15)
//    BR[N]   short8: [-2x0,-2x1,-2x2,1,1,0,0,0]    (B raw col, k=0..7)
//    BV[N]   short8: [0,0,0,0,0,-2u0,-2u1,-2u2]    (B vox col, k=0..7)
//    XXR[N], XXV[N] f32
#define WS_ACC 16
#define WS_TICKET 17
#define WS_GMIN 20
#define WS_MINS 32
#define MINS_TOTAL 65536
#define OFF_PACK (WS_MINS + MINS_TOTAL)
#define PERG 147456
#define OFF_AFLO(g) (OFF_PACK + (g)*PERG)
#define OFF_AFHI(g) (OFF_AFLO(g) + 32768)
#define OFF_BR(g)   (OFF_AFLO(g) + 65536)
#define OFF_BV(g)   (OFF_AFLO(g) + 98304)
#define OFF_XXR(g)  (OFF_AFLO(g) + 131072)
#define OFF_XXV(g)  (OFF_AFLO(g) + 139264)

typedef __attribute__((ext_vector_type(8))) short short8;    // 8 bf16 (MFMA A/B frag)
typedef __attribute__((ext_vector_type(16))) float f16v;     // 32x32 MFMA C/D frag

union S8 { short8 v; unsigned short u[8]; };

__device__ __forceinline__ unsigned short f2bf(float f) {    // RNE f32->bf16
    unsigned u = __float_as_uint(f);
    return (unsigned short)((u + 0x7FFFu + ((u >> 16) & 1u)) >> 16);
}
__device__ __forceinline__ float bf2f(unsigned short h) {
    return __uint_as_float(((unsigned)h) << 16);
}
__device__ __forceinline__ float voxq(float v, float g) {
    return (float)(int)((v - g) / VOXEL);   // trunc like .astype(int32)
}
// monotone float->uint (unsigned order == float order, handles negatives)
__device__ __forceinline__ unsigned fenc(float f) {
    const unsigned u = __float_as_uint(f);
    return (u & 0x80000000u) ? ~u : (u | 0x80000000u);
}
__device__ __forceinline__ float fdec(unsigned k) {
    const unsigned u = (k & 0x80000000u) ? (k & 0x7FFFFFFFu) : ~k;
    return __uint_as_float(u);
}

// 4 blocks (one per g), vectorized 3x float4 = 4 points per thread-iter.
__global__ void __launch_bounds__(PBLK)
gmin_kernel(const float* __restrict__ preds,
            const float* __restrict__ gts,
            float* __restrict__ ws) {
    const int g   = blockIdx.x;        // g = arr*2 + b
    const int arr = g >> 1;
    const int b   = g & 1;
    const float4* base4 = (const float4*)((arr ? gts : preds) + b * PTS_STRIDE);

    float m0 = INFINITY, m1 = INFINITY, m2 = INFINITY;
#pragma unroll
    for (int j = 0; j < 2; ++j) {
        const int i = j * PBLK + threadIdx.x;     // 0..2047, 4 points each
        const float4 q0 = base4[i*3+0];   // p0x p0y p0z p1x
        const float4 q1 = base4[i*3+1];   // p1y p1z p2x p2y
        const float4 q2 = base4[i*3+2];   // p2z p3x p3y p3z
        float v;
        v = q0.x; m0 = fminf(m0, (v!=v)?INFINITY:v);
        v = q0.w; m0 = fminf(m0, (v!=v)?INFINITY:v);
        v = q1.z; m0 = fminf(m0, (v!=v)?INFINITY:v);
        v = q2.y; m0 = fminf(m0, (v!=v)?INFINITY:v);
        v = q0.y; m1 = fminf(m1, (v!=v)?INFINITY:v);
        v = q1.x; m1 = fminf(m1, (v!=v)?INFINITY:v);
        v = q1.w; m1 = fminf(m1, (v!=v)?INFINITY:v);
        v = q2.z; m1 = fminf(m1, (v!=v)?INFINITY:v);
        v = q0.z; m2 = fminf(m2, (v!=v)?INFINITY:v);
        v = q1.y; m2 = fminf(m2, (v!=v)?INFINITY:v);
        v = q2.x; m2 = fminf(m2, (v!=v)?INFINITY:v);
        v = q2.w; m2 = fminf(m2, (v!=v)?INFINITY:v);
    }
    for (int off = 32; off; off >>= 1) {
        m0 = fminf(m0, __shfl_down(m0, off));
        m1 = fminf(m1, __shfl_down(m1, off));
        m2 = fminf(m2, __shfl_down(m2, off));
    }
    __shared__ float sm[16][3];
    const int wave = threadIdx.x >> 6, lane = threadIdx.x & 63;
    if (lane == 0) { sm[wave][0] = m0; sm[wave][1] = m1; sm[wave][2] = m2; }
    __syncthreads();
    if (threadIdx.x == 0) {
        float a0 = sm[0][0], a1 = sm[0][1], a2 = sm[0][2];
        for (int w = 1; w < 16; ++w) {
            a0 = fminf(a0, sm[w][0]);
            a1 = fminf(a1, sm[w][1]);
            a2 = fminf(a2, sm[w][2]);
        }
        ws[WS_GMIN + g*3+0] = a0; ws[WS_GMIN + g*3+1] = a1; ws[WS_GMIN + g*3+2] = a2;
        if (g == 0) { ws[WS_ACC] = 0.0f; ((unsigned*)ws)[WS_TICKET] = 0u; }
    }
}

// One thread per point (128 blocks x 256 = 32768): build fragments + init mins.
__global__ void __launch_bounds__(256)
pack_kernel(const float* __restrict__ preds,
            const float* __restrict__ gts,
            float* __restrict__ ws) {
    const int i   = blockIdx.x * 256 + threadIdx.x;   // 0..32767
    const int g   = i >> 13;
    const int idx = i & (N-1);
    const int arr = g >> 1;
    const int b   = g & 1;
    const float* base = (arr ? gts : preds) + b * PTS_STRIDE;

    // init encoded-min array (2 entries per thread): enc(+inf) = 0xFF800000
    unsigned* mins = (unsigned*)ws + WS_MINS;
    mins[i] = 0xFF800000u;
    mins[i + 32768] = 0xFF800000u;

    const float g0 = ws[WS_GMIN + g*3+0];
    const float g1 = ws[WS_GMIN + g*3+1];
    const float g2 = ws[WS_GMIN + g*3+2];

    const float p0 = base[idx*3+0], p1 = base[idx*3+1], p2 = base[idx*3+2];
    const float w0 = voxq(p0, g0), w1 = voxq(p1, g1), w2 = voxq(p2, g2);
    const float rr = fmaf(p0,p0, fmaf(p1,p1, p2*p2));
    const float vv = fmaf(w0,w0, fmaf(w1,w1, w2*w2));

    const unsigned short yyh = f2bf(rr);
    const unsigned short yyl = f2bf(rr - bf2f(yyh));
    const unsigned short vvh = f2bf(vv);
    const unsigned short vvl = f2bf(vv - bf2f(vvh));
    const unsigned short ONE = 0x3F80;

    short8* AFLO = (short8*)(ws + OFF_AFLO(g));
    short8* AFHI = (short8*)(ws + OFF_AFHI(g));
    short8* BR   = (short8*)(ws + OFF_BR(g));
    short8* BV   = (short8*)(ws + OFF_BV(g));

    S8 f;
    // A lo (k=0..7): [y0,y1,y2,yyh,yyl, w0,w1,w2]
    f.u[0]=f2bf(p0); f.u[1]=f2bf(p1); f.u[2]=f2bf(p2);
    f.u[3]=yyh; f.u[4]=yyl; f.u[5]=f2bf(w0); f.u[6]=f2bf(w1); f.u[7]=f2bf(w2);
    AFLO[idx] = f.v;
    // A hi (k=8..15): [vvh,vvl,0...]
    f.u[0]=vvh; f.u[1]=vvl; f.u[2]=0; f.u[3]=0; f.u[4]=0; f.u[5]=0; f.u[6]=0; f.u[7]=0;
    AFHI[idx] = f.v;
    // B raw col (k=0..7)
    f.u[0]=f2bf(-2.0f*p0); f.u[1]=f2bf(-2.0f*p1); f.u[2]=f2bf(-2.0f*p2);
    f.u[3]=ONE; f.u[4]=ONE; f.u[5]=0; f.u[6]=0; f.u[7]=0;
    BR[idx] = f.v;
    // B vox col (k=0..7)
    f.u[0]=0; f.u[1]=0; f.u[2]=0; f.u[3]=0; f.u[4]=0;
    f.u[5]=f2bf(-2.0f*w0); f.u[6]=f2bf(-2.0f*w1); f.u[7]=f2bf(-2.0f*w2);
    BV[idx] = f.v;
    ws[OFF_XXR(g) + idx] = rr;
    ws[OFF_XXV(g) + idx] = vv;
}

// Chamfer: 4096 blocks (256 xtiles x 4 ysplits x 4 slots) x 128 threads.
// 2 independent waves per block; wave w covers y in [(ysplit*2+w)*1024, +1024).
// Per wave: 2 fused B-frags (32 x-points; cols n<16 raw x_n, n>=16 vox x_{n-16}).
// A-frags straight from global (coalesced 16B/lane). No LDS, no __syncthreads.
// Combine: monotone-encoded atomicMin per (slot,var,x); |x|^2 added in finalize.
__global__ void __launch_bounds__(CBLK, 6)
chamfer_kernel(float* __restrict__ ws) {
    const int tid  = threadIdx.x;
    const int wave = tid >> 6, lane = tid & 63;
    const int half = lane >> 5, c32 = lane & 31;
    const int slot = blockIdx.z;           // 0..3
    const int dir  = slot & 1;
    const int b    = slot >> 1;
    const int gX = dir*2 + b;
    const int gY = (1-dir)*2 + b;

    const short8* Abase = (const short8*)(ws + (half ? OFF_AFHI(gY) : OFF_AFLO(gY)));
    const short8* BR = (const short8*)(ws + OFF_BR(gX));
    const short8* BV = (const short8*)(ws + OFF_BV(gX));

    // 2 fused B-frags for this block's 32 x
    const int xbase = blockIdx.x * 32;
    S8 hc;
    hc.u[0] = (c32 < 16) ? (unsigned short)0 : (unsigned short)0x3F80;
    hc.u[1] = hc.u[0];
    hc.u[2]=0; hc.u[3]=0; hc.u[4]=0; hc.u[5]=0; hc.u[6]=0; hc.u[7]=0;
    const int xcol0 = xbase + (c32 & 15);
    const short8 bf0 = (half == 0) ? ((c32 < 16) ? BR[xcol0] : BV[xcol0]) : hc.v;
    const short8 bf1 = (half == 0) ? ((c32 < 16) ? BR[xcol0+16] : BV[xcol0+16]) : hc.v;

    float mn0 = INFINITY, mn1 = INFINITY;
    const f16v Z = (f16v)(0.0f);
    const int abase0 = (blockIdx.y * 2 + wave) * 1024 + c32;

#pragma unroll 2
    for (int t = 0; t < 32; ++t) {         // 32 y-tiles of 32
        const short8 a = Abase[abase0 + t*32];
        const f16v d0 = __builtin_amdgcn_mfma_f32_32x32x16_bf16(a, bf0, Z, 0, 0, 0);
        {   // fold 16 -> mn0 (min3 tree)
            float t0 = fminf(fminf(d0[0], d0[1]),  fminf(d0[2], d0[3]));
            float t1 = fminf(fminf(d0[4], d0[5]),  fminf(d0[6], d0[7]));
            float t2 = fminf(fminf(d0[8], d0[9]),  fminf(d0[10], d0[11]));
            float t3 = fminf(fminf(d0[12], d0[13]), fminf(d0[14], d0[15]));
            mn0 = fminf(mn0, fminf(fminf(t0, t1), fminf(t2, t3)));
        }
        const f16v d1 = __builtin_amdgcn_mfma_f32_32x32x16_bf16(a, bf1, Z, 0, 0, 0);
        {
            float t0 = fminf(fminf(d1[0], d1[1]),  fminf(d1[2], d1[3]));
            float t1 = fminf(fminf(d1[4], d1[5]),  fminf(d1[6], d1[7]));
            float t2 = fminf(fminf(d1[8], d1[9]),  fminf(d1[10], d1[11]));
            float t3 = fminf(fminf(d1[12], d1[13]), fminf(d1[14], d1[15]));
            mn1 = fminf(mn1, fminf(fminf(t0, t1), fminf(t2, t3)));
        }
    }

    // other 16 rows live in the xor-32 partner lane (same column)
    mn0 = fminf(mn0, __shfl_xor(mn0, 32));
    mn1 = fminf(mn1, __shfl_xor(mn1, 32));

    if (half == 0) {
        unsigned* mins = (unsigned*)ws + WS_MINS;
        const int var = (c32 < 16) ? 0 : 1;
        const int e0 = ((slot*2 + var) << 13) + xcol0;
        atomicMin(&mins[e0],      fenc(mn0));
        atomicMin(&mins[e0 + 16], fenc(mn1));
    }
}

// 128 blocks x 256: one thread per (slot,x). Decode, add |x|^2, sum, ticket-out.
__global__ void __launch_bounds__(256)
finalize_kernel(float* __restrict__ ws, float* __restrict__ out) {
    const int g = blockIdx.x * 256 + threadIdx.x;   // 0..32767
    const int slot = g >> 13;
    const int x    = g & (N-1);
    const int dir  = slot & 1;
    const int b    = slot >> 1;
    const int gX   = dir*2 + b;
    const unsigned* mins = (const unsigned*)ws + WS_MINS;
    float s = fdec(mins[((slot*2 + 0) << 13) + x]) + ws[OFF_XXR(gX) + x]
            + fdec(mins[((slot*2 + 1) << 13) + x]) + ws[OFF_XXV(gX) + x];
    for (int off = 32; off; off >>= 1)
        s += __shfl_down(s, off);
    __shared__ float sm[4];
    const int wave = threadIdx.x >> 6, lane = threadIdx.x & 63;
    if (lane == 0) sm[wave] = s;
    __syncthreads();
    if (threadIdx.x == 0) {
        const float bs = sm[0] + sm[1] + sm[2] + sm[3];
        atomicAdd(ws + WS_ACC, bs);
        __threadfence();
        const unsigned t = atomicAdd(&((unsigned*)ws)[WS_TICKET], 1u);
        if (t == gridDim.x - 1) {
            __threadfence();
            const float total = atomicAdd(ws + WS_ACC, 0.0f);  // atomic read
            out[0] = total * (1.0f / 16384.0f);
        }
    }
}

extern "C" void kernel_launch(void* const* d_in, const int* in_sizes, int n_in,
                              void* d_out, int out_size, void* d_ws, size_t ws_size,
                              hipStream_t stream) {
    const float* preds = (const float*)d_in[0];
    const float* gts   = (const float*)d_in[1];
    float* ws  = (float*)d_ws;
    float* out = (float*)d_out;

    gmin_kernel<<<dim3(4), dim3(PBLK), 0, stream>>>(preds, gts, ws);
    pack_kernel<<<dim3(128), dim3(256), 0, stream>>>(preds, gts, ws);
    chamfer_kernel<<<dim3(N/32, 4, 4), dim3(CBLK), 0, stream>>>(ws);
    finalize_kernel<<<dim3(128), dim3(256), 0, stream>>>(ws, out);
}